// Round 3
// baseline (2429.693 us; speedup 1.0000x reference)
//
#include <hip/hip_runtime.h>
#include <hip/hip_fp16.h>

#define TSEQ   2048
#define NB     64
#define NE     256
#define NH     256
#define NG     768
#define TCH    64
#define NCHUNK (TSEQ / TCH)

using half2_t = __attribute__((ext_vector_type(2))) _Float16;
typedef unsigned int u32x4 __attribute__((ext_vector_type(4)));
union U4 { u32x4 q; half2_t h[4]; };

__device__ __forceinline__ float dot2f(half2_t a, half2_t b, float c) {
#if __has_builtin(__builtin_amdgcn_fdot2)
  return __builtin_amdgcn_fdot2(a, b, c, false);
#else
  return c + (float)a[0] * (float)b[0] + (float)a[1] * (float)b[1];
#endif
}

__device__ __forceinline__ float fast_exp2(float x) {
#if __has_builtin(__builtin_amdgcn_exp2f)
  return __builtin_amdgcn_exp2f(x);
#else
  return exp2f(x);
#endif
}
__device__ __forceinline__ float fast_rcp(float x) {
#if __has_builtin(__builtin_amdgcn_rcpf)
  return __builtin_amdgcn_rcpf(x);
#else
  return 1.f / x;
#endif
}
__device__ __forceinline__ float sigm(float x) {
  return fast_rcp(1.f + fast_exp2(x * -1.44269504f));
}
__device__ __forceinline__ float tanh_fast(float x) {
  x = fminf(x, 15.f);
  float e = fast_exp2(x * 2.88539008f);
  return (e - 1.f) * fast_rcp(e + 1.f);
}

// ---------------------------------------------------------------------------
// Pack w_hh (fp32 [768][256]) into fp16 pairs: w16[((k2b*NG + row)<<2) | q],
// k2 = 4*k2b + q covers elements (2*k2, 2*k2+1).
// ---------------------------------------------------------------------------
__global__ void prep_whh(const float* __restrict__ whh, unsigned int* __restrict__ w16) {
  int idx = blockIdx.x * 256 + threadIdx.x;
  if (idx >= 128 * NG) return;
  int row = idx % NG;
  int k2  = idx / NG;
  half2_t p;
  p[0] = (_Float16)whh[row * NH + 2 * k2];
  p[1] = (_Float16)whh[row * NH + 2 * k2 + 1];
  union { half2_t h; unsigned int u; } cvt;
  cvt.h = p;
  w16[(((k2 >> 2) * NG + row) << 2) | (k2 & 3)] = cvt.u;
}

// ---------------------------------------------------------------------------
// Fused per-chunk kernel. blocks [0,rec_count): recurrence (1 block = 1 batch).
// blocks [rec_count, rec_count+192): gi GEMM for the NEXT chunk (64 t x 3 g-regions).
// Static LDS ~88KB -> at most ONE block per CU (no co-residency).
// ---------------------------------------------------------------------------
__global__ __launch_bounds__(512) __attribute__((amdgpu_waves_per_eu(2, 2)))
void fused_kernel(const int* __restrict__ seq, const float* __restrict__ emb,
                  const float* __restrict__ wih, const float* __restrict__ bih,
                  const float* __restrict__ bhh, const unsigned int* __restrict__ w16,
                  const float* __restrict__ rec_gi, float* __restrict__ gi_dst,
                  int gi_t0, float* __restrict__ h_state, float* __restrict__ out,
                  int rec_count, int chunk)
{
  __shared__ __align__(16) _Float16 h16[2][NH];     //  1 KB
  __shared__ __align__(16) float    xs[64][68];     // 17.4 KB
  __shared__ __align__(16) float    wsh[256][68];   // 69.6 KB  (total ~88KB -> 1 block/CU)
  __shared__ int tok[64];

  const int tid = threadIdx.x;

  if ((int)blockIdx.x < rec_count) {
    // ======================= recurrence =======================
    const int b    = blockIdx.x;
    const int lane = tid & 63;
    const int wv   = tid >> 6;
    const int jj   = lane & 31;
    const int s    = lane >> 5;          // k-half; partner lane is lane^32
    const int j    = wv * 32 + jj;       // hidden index 0..255

    // weights in registers: 3 gate rows x 16 u32x4 = 192 VGPRs
    u32x4 wr[16], wz[16], wn[16];
#pragma unroll
    for (int i = 0; i < 16; ++i) {
      const int k2b = s * 16 + i;
      const unsigned int* base = w16 + (((size_t)k2b * NG) << 2);
      wr[i] = *(const u32x4*)(base + ((size_t)j << 2));
      wz[i] = *(const u32x4*)(base + ((size_t)(NH + j) << 2));
      wn[i] = *(const u32x4*)(base + ((size_t)(2 * NH + j) << 2));
    }
    // Opaque-ify: values now originate from asm -> cannot be rematerialized/
    // re-loaded inside the loop; allocator must keep them in VGPRs.
#pragma unroll
    for (int i = 0; i < 16; ++i) {
      asm volatile("" : "+v"(wr[i]), "+v"(wz[i]), "+v"(wn[i]));
    }

    const float bn = bhh[2 * NH + j];
    float hreg = 0.f;
    if (chunk != 0) hreg = h_state[b * NH + j];
    if (s == 0) h16[0][j] = (_Float16)hreg;
    __syncthreads();

    const float* gbase = rec_gi + (size_t)b * NG;
    float gr = gbase[j], gz = gbase[NH + j], gn = gbase[2 * NH + j];

#pragma unroll 1
    for (int t = 0; t < TCH; ++t) {
      const int tn = (t + 1) & (TCH - 1);
      const float* gt = gbase + (size_t)tn * NB * NG;
      float grn = gt[j], gzn = gt[NH + j], gnn = gt[2 * NH + j];

      float ar = 0.f, az = 0.f, an = 0.f;
      const char* hb = (const char*)h16 + ((t & 1) << 9) + (s << 8);
#pragma unroll
      for (int i = 0; i < 16; ++i) {
        U4 hu; hu.q = *(const u32x4*)(hb + (i << 4));  // wave-uniform per half -> broadcast
        U4 ru; ru.q = wr[i];
        U4 zu; zu.q = wz[i];
        U4 nu; nu.q = wn[i];
#pragma unroll
        for (int q = 0; q < 4; ++q) {
          ar = dot2f(hu.h[q], ru.h[q], ar);
          az = dot2f(hu.h[q], zu.h[q], az);
          an = dot2f(hu.h[q], nu.h[q], an);
        }
      }
      ar += __shfl_xor(ar, 32, 64);
      az += __shfl_xor(az, 32, 64);
      an += __shfl_xor(an, 32, 64);

      const float r = sigm(gr + ar);
      const float z = sigm(gz + az);
      const float n = tanh_fast(gn + r * (an + bn));
      hreg = n + z * (hreg - n);

      if (s == 0) h16[(t + 1) & 1][j] = (_Float16)hreg;
      gr = grn; gz = gzn; gn = gnn;
      __syncthreads();
    }
    if (s == 0) {
      h_state[b * NH + j] = hreg;
      if (out) out[b * NH + j] = hreg;
    }
  } else {
    // ======================= gi GEMM ==========================
    if (gi_dst == nullptr) return;
    const int gb   = blockIdx.x - rec_count;   // 0..191
    const int tl   = gb & 63;                  // local timestep
    const int greg = gb >> 6;                  // 0..2
    const int g0   = greg * 256;
    const int t    = gi_t0 + tl;
    if (tid < 64) tok[tid] = seq[tid * TSEQ + t];
    const int tx = tid & 31;                   // 32 col groups
    const int ty = tid >> 5;                   // 16 row groups of 4
    float acc[4][8];
#pragma unroll
    for (int i = 0; i < 4; ++i)
#pragma unroll
      for (int c8 = 0; c8 < 8; ++c8) acc[i][c8] = 0.f;

    for (int kb = 0; kb < 4; ++kb) {
      __syncthreads();                         // covers tok on first iter
#pragma unroll
      for (int it = 0; it < 2; ++it) {
        int i = it * 512 + tid;
        int r = i >> 4, c = i & 15;
        *(float4*)(&xs[r][c * 4]) =
            *(const float4*)(emb + (size_t)tok[r] * NE + kb * 64 + c * 4);
      }
#pragma unroll
      for (int it = 0; it < 8; ++it) {
        int i = it * 512 + tid;
        int r = i >> 4, c = i & 15;
        *(float4*)(&wsh[r][c * 4]) =
            *(const float4*)(wih + (size_t)(g0 + r) * NE + kb * 64 + c * 4);
      }
      __syncthreads();
#pragma unroll 4
      for (int k4 = 0; k4 < 16; ++k4) {
        float4 xf[4], wf[8];
#pragma unroll
        for (int i = 0; i < 4; ++i) xf[i] = *(const float4*)(&xs[ty * 4 + i][k4 * 4]);
#pragma unroll
        for (int c8 = 0; c8 < 8; ++c8) wf[c8] = *(const float4*)(&wsh[tx + 32 * c8][k4 * 4]);
#pragma unroll
        for (int i = 0; i < 4; ++i)
#pragma unroll
          for (int c8 = 0; c8 < 8; ++c8)
            acc[i][c8] += xf[i].x * wf[c8].x + xf[i].y * wf[c8].y +
                          xf[i].z * wf[c8].z + xf[i].w * wf[c8].w;
      }
    }
#pragma unroll
    for (int i = 0; i < 4; ++i) {
      const int brow = ty * 4 + i;
      float* dst = gi_dst + ((size_t)(tl * NB + brow)) * NG + g0;
#pragma unroll
      for (int c8 = 0; c8 < 8; ++c8) {
        const int col = tx + 32 * c8;
        const int g = g0 + col;
        float bias = bih[g] + (g < 2 * NH ? bhh[g] : 0.f);
        dst[col] = acc[i][c8] + bias;
      }
    }
  }
}

extern "C" void kernel_launch(void* const* d_in, const int* in_sizes, int n_in,
                              void* d_out, int out_size, void* d_ws, size_t ws_size,
                              hipStream_t stream) {
  (void)in_sizes; (void)n_in; (void)out_size; (void)ws_size;
  const int*   seq = (const int*)d_in[0];
  const float* emb = (const float*)d_in[1];
  const float* wih = (const float*)d_in[2];
  const float* whh = (const float*)d_in[3];
  const float* bih = (const float*)d_in[4];
  const float* bhh = (const float*)d_in[5];
  float* out = (float*)d_out;
  char*  ws  = (char*)d_ws;

  unsigned int* w16     = (unsigned int*)(ws);            // 393,216 B
  float*        h_state = (float*)(ws + 393216);          //  65,536 B
  float*        gi0     = (float*)(ws + 458752);          // 12,582,912 B
  float*        gi1     = (float*)(ws + 458752 + 12582912);

  prep_whh<<<dim3(384), dim3(256), 0, stream>>>(whh, w16);

  // prologue: gi for chunk 0 only
  fused_kernel<<<dim3(192), dim3(512), 0, stream>>>(
      seq, emb, wih, bih, bhh, w16,
      nullptr, gi0, 0, h_state, nullptr, 0, 0);

  for (int c = 0; c < NCHUNK; ++c) {
    float* rd  = (c & 1) ? gi1 : gi0;
    float* wr_ = (c & 1) ? gi0 : gi1;
    const bool last = (c == NCHUNK - 1);
    const int grid  = last ? NB : NB + 192;
    fused_kernel<<<dim3(grid), dim3(512), 0, stream>>>(
        seq, emb, wih, bih, bhh, w16,
        rd, last ? nullptr : wr_, (c + 1) * TCH, h_state,
        last ? out : nullptr, NB, c);
  }
}